// Round 3
// baseline (651.038 us; speedup 1.0000x reference)
//
#include <hip/hip_runtime.h>

#define DD 128

typedef __attribute__((ext_vector_type(8))) short short8;
typedef __attribute__((ext_vector_type(4))) float f32x4;
typedef unsigned short u16;
typedef unsigned int u32;

__device__ __forceinline__ u16 f2bf(float f) {
  u32 u = __builtin_bit_cast(u32, f);
  u += 0x7fffu + ((u >> 16) & 1u);
  return (u16)(u >> 16);
}
__device__ __forceinline__ float bf2f(u16 s) {
  u32 u = ((u32)s) << 16;
  return __builtin_bit_cast(float, u);
}
__device__ __forceinline__ float sigmoidf_(float v) { return 1.f / (1.f + __expf(-v)); }
__device__ __forceinline__ float tanhf_(float v) {
  float e = __expf(-2.f * v);
  return (1.f - e) / (1.f + e);
}

struct WPtrs { const float* w[10]; };

// Pack W [k][n] (row-major fp32, 128x128) into fragment-major bf16:
// Bp[((ks*8+nt)*64 + lane)*8 + e] = bf16( W[ks*32 + (lane>>4)*8 + e][(lane&15) + nt*16] )
__global__ void pack_weights(WPtrs wp, u16* __restrict__ bp) {
  const float* W = wp.w[blockIdx.x];
  u16* out = bp + (size_t)blockIdx.x * 16384;
  for (int o = threadIdx.x; o < 16384; o += blockDim.x) {
    int e = o & 7, lane = (o >> 3) & 63, nt = (o >> 9) & 7, ks = o >> 12;
    int k = ks * 32 + (lane >> 4) * 8 + e;
    int c = (lane & 15) + nt * 16;
    out[o] = f2bf(W[k * DD + c]);
  }
}

__global__ void cvt_bf16(const float* __restrict__ in, u16* __restrict__ out, int n4) {
  int i = blockIdx.x * blockDim.x + threadIdx.x;
  if (i < n4) {
    float4 v = *reinterpret_cast<const float4*>(in + (size_t)i * 4);
    ushort4 o;
    o.x = f2bf(v.x); o.y = f2bf(v.y); o.z = f2bf(v.z); o.w = f2bf(v.w);
    *reinterpret_cast<ushort4*>(out + (size_t)i * 4) = o;
  }
}

__global__ void count_edges(const int* __restrict__ rows, int* __restrict__ counts, int E) {
  int i = blockIdx.x * blockDim.x + threadIdx.x;
  if (i < E) atomicAdd(&counts[rows[i]], 1);
}

// single-block scan: 1024 thr x 8 elem/thr per chunk; wave shfl-scan + 16-wave LDS scan
__global__ __launch_bounds__(1024) void scan_offsets(const int* __restrict__ counts,
                                                     int* __restrict__ offs,
                                                     int* __restrict__ cursor, int n) {
  __shared__ int wtot[16];
  __shared__ int chunk_tot_sm;
  const int t = threadIdx.x;
  const int lane = t & 63, w = t >> 6;
  int running = 0;
  for (int base = 0; base < n; base += 8192) {
    int v[8];
    int s = 0;
    const int i0 = base + t * 8;
#pragma unroll
    for (int j = 0; j < 8; ++j) {
      int i = i0 + j;
      v[j] = (i < n) ? counts[i] : 0;
      s += v[j];
    }
    // wave inclusive scan of per-thread sums
    int incl = s;
#pragma unroll
    for (int o = 1; o < 64; o <<= 1) {
      int x = __shfl_up(incl, o, 64);
      if (lane >= o) incl += x;
    }
    if (lane == 63) wtot[w] = incl;
    __syncthreads();
    if (w == 0 && lane < 16) {
      int x = wtot[lane];
#pragma unroll
      for (int o = 1; o < 16; o <<= 1) {
        int y = __shfl_up(x, o, 64);
        if (lane >= o) x += y;
      }
      wtot[lane] = x;
      if (lane == 15) chunk_tot_sm = x;
    }
    __syncthreads();
    int wexcl = (w == 0) ? 0 : wtot[w - 1];
    int p = running + wexcl + (incl - s);  // exclusive prefix for this thread
#pragma unroll
    for (int j = 0; j < 8; ++j) {
      int i = i0 + j;
      if (i < n) { offs[i] = p; cursor[i] = p; }
      p += v[j];
    }
    running += chunk_tot_sm;
    __syncthreads();  // protect wtot/chunk_tot_sm reuse next chunk
  }
  if (t == 0) offs[n] = running;
}

__global__ void permute_edges(const int* __restrict__ rows, const int* __restrict__ cols,
                              const float* __restrict__ vals, int* __restrict__ cursor,
                              int* __restrict__ ecol, float* __restrict__ eval, int E) {
  int i = blockIdx.x * blockDim.x + threadIdx.x;
  if (i < E) {
    int r = rows[i];
    int p = atomicAdd(&cursor[r], 1);
    ecol[p] = cols[i];
    eval[p] = vals[i];
  }
}

// one wave per row; lane handles 2 consecutive d's (one 256B row per gather)
__global__ void spmm_agg(const int* __restrict__ offs, const int* __restrict__ ecol,
                         const float* __restrict__ eval, const u16* __restrict__ xb,
                         u16* __restrict__ aggb, int n) {
  int row = blockIdx.x * 4 + (threadIdx.x >> 6);
  int lane = threadIdx.x & 63;
  if (row >= n) return;
  int s = offs[row], e2 = offs[row + 1];
  float a0 = 0.f, a1 = 0.f;
  int j = s;
  for (; j + 1 < e2; j += 2) {
    int c0 = ecol[j], c1 = ecol[j + 1];
    float v0 = eval[j], v1 = eval[j + 1];
    u32 x0 = *reinterpret_cast<const u32*>(xb + (size_t)c0 * DD + lane * 2);
    u32 x1 = *reinterpret_cast<const u32*>(xb + (size_t)c1 * DD + lane * 2);
    a0 += v0 * bf2f((u16)(x0 & 0xffff)) + v1 * bf2f((u16)(x1 & 0xffff));
    a1 += v0 * bf2f((u16)(x0 >> 16)) + v1 * bf2f((u16)(x1 >> 16));
  }
  if (j < e2) {
    int c0 = ecol[j];
    float v0 = eval[j];
    u32 x0 = *reinterpret_cast<const u32*>(xb + (size_t)c0 * DD + lane * 2);
    a0 += v0 * bf2f((u16)(x0 & 0xffff));
    a1 += v0 * bf2f((u16)(x0 >> 16));
  }
  u32 o = ((u32)f2bf(a1) << 16) | (u32)f2bf(a0);
  *reinterpret_cast<u32*>(aggb + (size_t)row * DD + lane * 2) = o;
}

// MODE 0: relu -> bf16 ; MODE 2: -> bf16
template <int MODE>
__global__ __launch_bounds__(256) void gemm128(const u16* __restrict__ A,
                                               const u16* __restrict__ Bp,
                                               const float* __restrict__ bias,
                                               u16* __restrict__ outB, int n) {
  const int lane = threadIdx.x & 63;
  const int wid = threadIdx.x >> 6;
  const int row0 = blockIdx.x * 128 + wid * 32;
  f32x4 acc[2][8];
#pragma unroll
  for (int m = 0; m < 2; ++m)
#pragma unroll
    for (int t = 0; t < 8; ++t) acc[m][t] = f32x4{0.f, 0.f, 0.f, 0.f};

  const int ar = lane & 15, ak = (lane >> 4) * 8;
#pragma unroll
  for (int ks = 0; ks < 4; ++ks) {
    short8 a[2];
#pragma unroll
    for (int m = 0; m < 2; ++m) {
      int r = row0 + m * 16 + ar;
      r = r < n ? r : n - 1;
      a[m] = *reinterpret_cast<const short8*>(A + (size_t)r * DD + ks * 32 + ak);
    }
#pragma unroll
    for (int nt = 0; nt < 8; ++nt) {
      short8 b = *reinterpret_cast<const short8*>(Bp + (((ks * 8 + nt) * 64 + lane) * 8));
#pragma unroll
      for (int m = 0; m < 2; ++m)
        acc[m][nt] = __builtin_amdgcn_mfma_f32_16x16x32_bf16(a[m], b, acc[m][nt], 0, 0, 0);
    }
  }
  const int crow = 4 * (lane >> 4), ccol = lane & 15;
#pragma unroll
  for (int m = 0; m < 2; ++m) {
#pragma unroll
    for (int nt = 0; nt < 8; ++nt) {
      int col = ccol + nt * 16;
      float bsv = bias[col];
#pragma unroll
      for (int e = 0; e < 4; ++e) {
        int r = row0 + m * 16 + crow + e;
        if (r < n) {
          float v = acc[m][nt][e] + bsv;
          if (MODE == 0) v = v > 0.f ? v : 0.f;
          outB[(size_t)r * DD + col] = f2bf(v);
        }
      }
    }
  }
}

// fused 5-GEMM gates: z = sig(out@Wu1+x@Wu2+b) ; r = sig(out@Wr1+x@Wr2+b) ; oi1 = out@Wo1+bo1
__global__ __launch_bounds__(256) void gates_gemm(
    const u16* __restrict__ Ao, const u16* __restrict__ Ax, const u16* __restrict__ Wu1p,
    const u16* __restrict__ Wu2p, const u16* __restrict__ Wr1p, const u16* __restrict__ Wr2p,
    const u16* __restrict__ Wo1p, const float* __restrict__ bu1, const float* __restrict__ bu2,
    const float* __restrict__ br1, const float* __restrict__ br2, const float* __restrict__ bo1,
    u16* __restrict__ zb, u16* __restrict__ rxb, u16* __restrict__ oi1b, int n) {
  const int lane = threadIdx.x & 63;
  const int wid = threadIdx.x >> 6;
  const int row0 = blockIdx.x * 64 + wid * 16;
  f32x4 aZ[8], aR[8], aO[8];
#pragma unroll
  for (int t = 0; t < 8; ++t) {
    aZ[t] = f32x4{0.f, 0.f, 0.f, 0.f};
    aR[t] = f32x4{0.f, 0.f, 0.f, 0.f};
    aO[t] = f32x4{0.f, 0.f, 0.f, 0.f};
  }
  const int ar = lane & 15, ak = (lane >> 4) * 8;
#pragma unroll
  for (int ks = 0; ks < 4; ++ks) {
    int r = row0 + ar;
    r = r < n ? r : n - 1;
    short8 ao = *reinterpret_cast<const short8*>(Ao + (size_t)r * DD + ks * 32 + ak);
    short8 ax = *reinterpret_cast<const short8*>(Ax + (size_t)r * DD + ks * 32 + ak);
#pragma unroll
    for (int nt = 0; nt < 8; ++nt) {
      size_t bo = (size_t)(((ks * 8 + nt) * 64 + lane) * 8);
      short8 b1 = *reinterpret_cast<const short8*>(Wu1p + bo);
      short8 b2 = *reinterpret_cast<const short8*>(Wu2p + bo);
      short8 b3 = *reinterpret_cast<const short8*>(Wr1p + bo);
      short8 b4 = *reinterpret_cast<const short8*>(Wr2p + bo);
      short8 b5 = *reinterpret_cast<const short8*>(Wo1p + bo);
      aZ[nt] = __builtin_amdgcn_mfma_f32_16x16x32_bf16(ao, b1, aZ[nt], 0, 0, 0);
      aZ[nt] = __builtin_amdgcn_mfma_f32_16x16x32_bf16(ax, b2, aZ[nt], 0, 0, 0);
      aR[nt] = __builtin_amdgcn_mfma_f32_16x16x32_bf16(ao, b3, aR[nt], 0, 0, 0);
      aR[nt] = __builtin_amdgcn_mfma_f32_16x16x32_bf16(ax, b4, aR[nt], 0, 0, 0);
      aO[nt] = __builtin_amdgcn_mfma_f32_16x16x32_bf16(ao, b5, aO[nt], 0, 0, 0);
    }
  }
  const int crow = 4 * (lane >> 4), ccol = lane & 15;
#pragma unroll
  for (int nt = 0; nt < 8; ++nt) {
    int col = ccol + nt * 16;
    float bz = bu1[col] + bu2[col];
    float br_ = br1[col] + br2[col];
    float bo_ = bo1[col];
#pragma unroll
    for (int e = 0; e < 4; ++e) {
      int r = row0 + crow + e;
      if (r < n) {
        size_t idx = (size_t)r * DD + col;
        float z = sigmoidf_(aZ[nt][e] + bz);
        float rr = sigmoidf_(aR[nt][e] + br_);
        float xv = bf2f(Ax[idx]);
        zb[idx] = f2bf(z);
        rxb[idx] = f2bf(rr * xv);
        oi1b[idx] = f2bf(aO[nt][e] + bo_);
      }
    }
  }
}

// final: oi = rx@Wo2 + bo2 + oi1 ; h = tanh(oi); out = (1-z)*x + z*h
__global__ __launch_bounds__(256) void final_gemm(const u16* __restrict__ Arx,
                                                  const u16* __restrict__ Wo2p,
                                                  const float* __restrict__ bo2,
                                                  const u16* __restrict__ oi1b,
                                                  const u16* __restrict__ zb,
                                                  const u16* __restrict__ xb,
                                                  float* __restrict__ out, int n) {
  const int lane = threadIdx.x & 63;
  const int wid = threadIdx.x >> 6;
  const int row0 = blockIdx.x * 128 + wid * 32;
  f32x4 acc[2][8];
#pragma unroll
  for (int m = 0; m < 2; ++m)
#pragma unroll
    for (int t = 0; t < 8; ++t) acc[m][t] = f32x4{0.f, 0.f, 0.f, 0.f};
  const int ar = lane & 15, ak = (lane >> 4) * 8;
#pragma unroll
  for (int ks = 0; ks < 4; ++ks) {
    short8 a[2];
#pragma unroll
    for (int m = 0; m < 2; ++m) {
      int r = row0 + m * 16 + ar;
      r = r < n ? r : n - 1;
      a[m] = *reinterpret_cast<const short8*>(Arx + (size_t)r * DD + ks * 32 + ak);
    }
#pragma unroll
    for (int nt = 0; nt < 8; ++nt) {
      short8 b = *reinterpret_cast<const short8*>(Wo2p + (((ks * 8 + nt) * 64 + lane) * 8));
#pragma unroll
      for (int m = 0; m < 2; ++m)
        acc[m][nt] = __builtin_amdgcn_mfma_f32_16x16x32_bf16(a[m], b, acc[m][nt], 0, 0, 0);
    }
  }
  const int crow = 4 * (lane >> 4), ccol = lane & 15;
#pragma unroll
  for (int m = 0; m < 2; ++m) {
#pragma unroll
    for (int nt = 0; nt < 8; ++nt) {
      int col = ccol + nt * 16;
      float bsv = bo2[col];
#pragma unroll
      for (int e = 0; e < 4; ++e) {
        int r = row0 + m * 16 + crow + e;
        if (r < n) {
          size_t idx = (size_t)r * DD + col;
          float oi = acc[m][nt][e] + bsv + bf2f(oi1b[idx]);
          float h = tanhf_(oi);
          float z = bf2f(zb[idx]);
          float xv = bf2f(xb[idx]);
          out[idx] = (1.f - z) * xv + z * h;
        }
      }
    }
  }
}

extern "C" void kernel_launch(void* const* d_in, const int* in_sizes, int n_in,
                              void* d_out, int out_size, void* d_ws, size_t ws_size,
                              hipStream_t stream) {
  const int n = in_sizes[0] / DD;  // 50000
  const int E = in_sizes[1];       // 1.6M
  const float* x_in = (const float*)d_in[0];
  const int* rows = (const int*)d_in[1];
  const int* cols = (const int*)d_in[2];
  const float* vals = (const float*)d_in[3];
  const float* Wm[10];
  const float* Bm[10];
  for (int i = 0; i < 10; ++i) {
    Wm[i] = (const float*)d_in[4 + 2 * i];
    Bm[i] = (const float*)d_in[5 + 2 * i];
  }

  char* base = (char*)d_ws;
  size_t off = 0;
  auto alloc = [&](size_t bytes) -> char* {
    char* p = base + off;
    off += (bytes + 255) & ~(size_t)255;
    return p;
  };
  u16* wpack = (u16*)alloc((size_t)10 * 16384 * 2);
  u16* xin_b = (u16*)alloc((size_t)n * DD * 2);  // reused as rx_b after first gemm
  u16* h1_b = (u16*)alloc((size_t)n * DD * 2);
  u16* x_b = (u16*)alloc((size_t)n * DD * 2);
  u16* agg_b = (u16*)alloc((size_t)n * DD * 2);  // reused as out_b
  u16* z_b = (u16*)alloc((size_t)n * DD * 2);
  u16* oi1_b = (u16*)alloc((size_t)n * DD * 2);
  int* counts = (int*)alloc((size_t)n * 4);
  int* offs = (int*)alloc((size_t)(n + 1) * 4);
  int* cursor = (int*)alloc((size_t)n * 4);
  int* ecol = (int*)alloc((size_t)E * 4);
  float* eval = (float*)alloc((size_t)E * 4);
  u16* rx_b = xin_b;
  (void)ws_size;
  (void)n_in;
  (void)out_size;

  hipMemsetAsync(counts, 0, (size_t)n * 4, stream);
  WPtrs wp;
  for (int i = 0; i < 10; ++i) wp.w[i] = Wm[i];
  pack_weights<<<10, 256, 0, stream>>>(wp, wpack);
  int nd4 = n * DD / 4;
  cvt_bf16<<<(nd4 + 255) / 256, 256, 0, stream>>>(x_in, xin_b, nd4);
  count_edges<<<(E + 255) / 256, 256, 0, stream>>>(rows, counts, E);
  scan_offsets<<<1, 1024, 0, stream>>>(counts, offs, cursor, n);
  permute_edges<<<(E + 255) / 256, 256, 0, stream>>>(rows, cols, vals, cursor, ecol, eval, E);

  int gblocks = (n + 127) / 128;
  // x = mlp2(x_in, m1_*)
  gemm128<0><<<gblocks, 256, 0, stream>>>(xin_b, wpack + 0 * 16384, Bm[0], h1_b, n);
  gemm128<2><<<gblocks, 256, 0, stream>>>(h1_b, wpack + 1 * 16384, Bm[1], x_b, n);
  // agg = segment_sum(vals * x[cols], rows)
  spmm_agg<<<(n + 3) / 4, 256, 0, stream>>>(offs, ecol, eval, x_b, agg_b, n);
  // out = mlp2(agg, m2_*)
  gemm128<0><<<gblocks, 256, 0, stream>>>(agg_b, wpack + 2 * 16384, Bm[2], h1_b, n);
  gemm128<2><<<gblocks, 256, 0, stream>>>(h1_b, wpack + 3 * 16384, Bm[3], agg_b, n);
  // gates (writes rx_b which aliases xin_b -- xin_b dead after first gemm)
  gates_gemm<<<(n + 63) / 64, 256, 0, stream>>>(
      agg_b, x_b, wpack + 4 * 16384, wpack + 5 * 16384, wpack + 6 * 16384, wpack + 7 * 16384,
      wpack + 8 * 16384, Bm[4], Bm[5], Bm[6], Bm[7], Bm[8], z_b, rx_b, oi1_b, n);
  // final
  final_gemm<<<gblocks, 256, 0, stream>>>(rx_b, wpack + 9 * 16384, Bm[9], oi1_b, z_b, x_b,
                                          (float*)d_out, n);
}

// Round 4
// 595.804 us; speedup vs baseline: 1.0927x; 1.0927x over previous
//
#include <hip/hip_runtime.h>

#define DD 128

typedef __attribute__((ext_vector_type(8))) short short8;
typedef __attribute__((ext_vector_type(4))) float f32x4;
typedef unsigned short u16;
typedef unsigned int u32;

__device__ __forceinline__ u16 f2bf(float f) {
  u32 u = __builtin_bit_cast(u32, f);
  u += 0x7fffu + ((u >> 16) & 1u);
  return (u16)(u >> 16);
}
__device__ __forceinline__ float bf2f(u16 s) {
  u32 u = ((u32)s) << 16;
  return __builtin_bit_cast(float, u);
}
__device__ __forceinline__ float sigmoidf_(float v) { return 1.f / (1.f + __expf(-v)); }
__device__ __forceinline__ float tanhf_(float v) {
  float e = __expf(-2.f * v);
  return (1.f - e) / (1.f + e);
}

struct WPtrs { const float* w[10]; };

// Pack W [k][n] (row-major fp32, 128x128) into fragment-major bf16:
// Bp[((ks*8+nt)*64 + lane)*8 + e] = bf16( W[ks*32 + (lane>>4)*8 + e][(lane&15) + nt*16] )
__global__ void pack_weights(WPtrs wp, u16* __restrict__ bp) {
  const float* W = wp.w[blockIdx.x];
  u16* out = bp + (size_t)blockIdx.x * 16384;
  for (int o = threadIdx.x; o < 16384; o += blockDim.x) {
    int e = o & 7, lane = (o >> 3) & 63, nt = (o >> 9) & 7, ks = o >> 12;
    int k = ks * 32 + (lane >> 4) * 8 + e;
    int c = (lane & 15) + nt * 16;
    out[o] = f2bf(W[k * DD + c]);
  }
}

__global__ void count_edges(const int* __restrict__ rows, int* __restrict__ counts, int E) {
  int i = blockIdx.x * blockDim.x + threadIdx.x;
  if (i < E) atomicAdd(&counts[rows[i]], 1);
}

// single-block scan: 1024 thr x 8 elem/thr per chunk; wave shfl-scan + 16-wave LDS scan
__global__ __launch_bounds__(1024) void scan_offsets(const int* __restrict__ counts,
                                                     int* __restrict__ offs,
                                                     int* __restrict__ cursor, int n) {
  __shared__ int wtot[16];
  __shared__ int chunk_tot_sm;
  const int t = threadIdx.x;
  const int lane = t & 63, w = t >> 6;
  int running = 0;
  for (int base = 0; base < n; base += 8192) {
    int v[8];
    int s = 0;
    const int i0 = base + t * 8;
#pragma unroll
    for (int j = 0; j < 8; ++j) {
      int i = i0 + j;
      v[j] = (i < n) ? counts[i] : 0;
      s += v[j];
    }
    int incl = s;
#pragma unroll
    for (int o = 1; o < 64; o <<= 1) {
      int x = __shfl_up(incl, o, 64);
      if (lane >= o) incl += x;
    }
    if (lane == 63) wtot[w] = incl;
    __syncthreads();
    if (w == 0 && lane < 16) {
      int x = wtot[lane];
#pragma unroll
      for (int o = 1; o < 16; o <<= 1) {
        int y = __shfl_up(x, o, 64);
        if (lane >= o) x += y;
      }
      wtot[lane] = x;
      if (lane == 15) chunk_tot_sm = x;
    }
    __syncthreads();
    int wexcl = (w == 0) ? 0 : wtot[w - 1];
    int p = running + wexcl + (incl - s);
#pragma unroll
    for (int j = 0; j < 8; ++j) {
      int i = i0 + j;
      if (i < n) { offs[i] = p; cursor[i] = p; }
      p += v[j];
    }
    running += chunk_tot_sm;
    __syncthreads();
  }
  if (t == 0) offs[n] = running;
}

// scatter a single packed 4B record per edge: (col << 16) | fp16(val)
__global__ void permute_edges(const int* __restrict__ rows, const int* __restrict__ cols,
                              const float* __restrict__ vals, int* __restrict__ cursor,
                              u32* __restrict__ epack, int E) {
  int i = blockIdx.x * blockDim.x + threadIdx.x;
  if (i < E) {
    int r = rows[i];
    int p = atomicAdd(&cursor[r], 1);
    _Float16 hf = (_Float16)vals[i];
    u32 hb = (u32)__builtin_bit_cast(u16, hf);
    epack[p] = ((u32)cols[i] << 16) | hb;
  }
}

// one wave per row; lane handles 2 consecutive d's (one 256B row per gather)
__global__ void spmm_agg(const int* __restrict__ offs, const u32* __restrict__ epack,
                         const u16* __restrict__ xb, u16* __restrict__ aggb, int n) {
  int row = blockIdx.x * 4 + (threadIdx.x >> 6);
  int lane = threadIdx.x & 63;
  if (row >= n) return;
  int s = offs[row], e2 = offs[row + 1];
  float a0 = 0.f, a1 = 0.f;
  int j = s;
  for (; j + 3 < e2; j += 4) {
    u32 pk0 = epack[j], pk1 = epack[j + 1], pk2 = epack[j + 2], pk3 = epack[j + 3];
    u32 x0 = *reinterpret_cast<const u32*>(xb + (size_t)(pk0 >> 16) * DD + lane * 2);
    u32 x1 = *reinterpret_cast<const u32*>(xb + (size_t)(pk1 >> 16) * DD + lane * 2);
    u32 x2 = *reinterpret_cast<const u32*>(xb + (size_t)(pk2 >> 16) * DD + lane * 2);
    u32 x3 = *reinterpret_cast<const u32*>(xb + (size_t)(pk3 >> 16) * DD + lane * 2);
    float v0 = (float)__builtin_bit_cast(_Float16, (u16)(pk0 & 0xffffu));
    float v1 = (float)__builtin_bit_cast(_Float16, (u16)(pk1 & 0xffffu));
    float v2 = (float)__builtin_bit_cast(_Float16, (u16)(pk2 & 0xffffu));
    float v3 = (float)__builtin_bit_cast(_Float16, (u16)(pk3 & 0xffffu));
    a0 += v0 * bf2f((u16)(x0 & 0xffff)) + v1 * bf2f((u16)(x1 & 0xffff)) +
          v2 * bf2f((u16)(x2 & 0xffff)) + v3 * bf2f((u16)(x3 & 0xffff));
    a1 += v0 * bf2f((u16)(x0 >> 16)) + v1 * bf2f((u16)(x1 >> 16)) +
          v2 * bf2f((u16)(x2 >> 16)) + v3 * bf2f((u16)(x3 >> 16));
  }
  for (; j < e2; ++j) {
    u32 pk = epack[j];
    u32 x0 = *reinterpret_cast<const u32*>(xb + (size_t)(pk >> 16) * DD + lane * 2);
    float v0 = (float)__builtin_bit_cast(_Float16, (u16)(pk & 0xffffu));
    a0 += v0 * bf2f((u16)(x0 & 0xffff));
    a1 += v0 * bf2f((u16)(x0 >> 16));
  }
  u32 o = ((u32)f2bf(a1) << 16) | (u32)f2bf(a0);
  *reinterpret_cast<u32*>(aggb + (size_t)row * DD + lane * 2) = o;
}

// Fused 2-layer MLP: out = (relu(A@W1+b1))@W2 + b2, bf16 out.
// ASRC 0: A is fp32; ASRC 1: A is bf16. Per-wave private LDS tile for h1.
// LDS row stride 136 u16 = 272B (16B-aligned; bank stride 4 -> <=2-way conflicts).
template <int ASRC>
__global__ __launch_bounds__(256) void mlp_fused(const void* __restrict__ Ain,
                                                 const u16* __restrict__ W1p,
                                                 const float* __restrict__ b1,
                                                 const u16* __restrict__ W2p,
                                                 const float* __restrict__ b2,
                                                 u16* __restrict__ outB, int n) {
  __shared__ u16 sm[4][32][136];
  const int lane = threadIdx.x & 63;
  const int wid = threadIdx.x >> 6;
  const int row0 = blockIdx.x * 128 + wid * 32;
  const int ar = lane & 15, ak = (lane >> 4) * 8;
  const int crow = 4 * (lane >> 4), ccol = lane & 15;

  f32x4 acc[2][8];
#pragma unroll
  for (int m = 0; m < 2; ++m)
#pragma unroll
    for (int t = 0; t < 8; ++t) acc[m][t] = f32x4{0.f, 0.f, 0.f, 0.f};

#pragma unroll
  for (int ks = 0; ks < 4; ++ks) {
    short8 a[2];
#pragma unroll
    for (int m = 0; m < 2; ++m) {
      int r = row0 + m * 16 + ar;
      r = r < n ? r : n - 1;
      if (ASRC == 0) {
        const float* Ap = (const float*)Ain + (size_t)r * DD + ks * 32 + ak;
        float4 f0 = *reinterpret_cast<const float4*>(Ap);
        float4 f1 = *reinterpret_cast<const float4*>(Ap + 4);
        short8 t;
        t[0] = (short)f2bf(f0.x); t[1] = (short)f2bf(f0.y);
        t[2] = (short)f2bf(f0.z); t[3] = (short)f2bf(f0.w);
        t[4] = (short)f2bf(f1.x); t[5] = (short)f2bf(f1.y);
        t[6] = (short)f2bf(f1.z); t[7] = (short)f2bf(f1.w);
        a[m] = t;
      } else {
        a[m] = *reinterpret_cast<const short8*>((const u16*)Ain + (size_t)r * DD + ks * 32 + ak);
      }
    }
#pragma unroll
    for (int nt = 0; nt < 8; ++nt) {
      short8 b = *reinterpret_cast<const short8*>(W1p + (((ks * 8 + nt) * 64 + lane) * 8));
#pragma unroll
      for (int m = 0; m < 2; ++m)
        acc[m][nt] = __builtin_amdgcn_mfma_f32_16x16x32_bf16(a[m], b, acc[m][nt], 0, 0, 0);
    }
  }
  // epilogue 1: bias + relu -> LDS (wave-private tile)
#pragma unroll
  for (int m = 0; m < 2; ++m)
#pragma unroll
    for (int nt = 0; nt < 8; ++nt) {
      float bsv = b1[ccol + nt * 16];
#pragma unroll
      for (int e = 0; e < 4; ++e) {
        float v = acc[m][nt][e] + bsv;
        v = v > 0.f ? v : 0.f;
        sm[wid][m * 16 + crow + e][ccol + nt * 16] = f2bf(v);
      }
    }
  __syncthreads();

  // GEMM2 from LDS
  f32x4 acc2[2][8];
#pragma unroll
  for (int m = 0; m < 2; ++m)
#pragma unroll
    for (int t = 0; t < 8; ++t) acc2[m][t] = f32x4{0.f, 0.f, 0.f, 0.f};
#pragma unroll
  for (int ks = 0; ks < 4; ++ks) {
    short8 a2[2];
#pragma unroll
    for (int m = 0; m < 2; ++m)
      a2[m] = *reinterpret_cast<const short8*>(&sm[wid][m * 16 + ar][ks * 32 + ak]);
#pragma unroll
    for (int nt = 0; nt < 8; ++nt) {
      short8 b = *reinterpret_cast<const short8*>(W2p + (((ks * 8 + nt) * 64 + lane) * 8));
#pragma unroll
      for (int m = 0; m < 2; ++m)
        acc2[m][nt] = __builtin_amdgcn_mfma_f32_16x16x32_bf16(a2[m], b, acc2[m][nt], 0, 0, 0);
    }
  }
#pragma unroll
  for (int m = 0; m < 2; ++m)
#pragma unroll
    for (int nt = 0; nt < 8; ++nt) {
      int col = ccol + nt * 16;
      float bsv = b2[col];
#pragma unroll
      for (int e = 0; e < 4; ++e) {
        int r = row0 + m * 16 + crow + e;
        if (r < n) outB[(size_t)r * DD + col] = f2bf(acc2[m][nt][e] + bsv);
      }
    }
}

// fused 5-GEMM gates: z = sig(out@Wu1+x@Wu2+b) ; r = sig(out@Wr1+x@Wr2+b) ; oi1 = out@Wo1+bo1
__global__ __launch_bounds__(256) void gates_gemm(
    const u16* __restrict__ Ao, const u16* __restrict__ Ax, const u16* __restrict__ Wu1p,
    const u16* __restrict__ Wu2p, const u16* __restrict__ Wr1p, const u16* __restrict__ Wr2p,
    const u16* __restrict__ Wo1p, const float* __restrict__ bu1, const float* __restrict__ bu2,
    const float* __restrict__ br1, const float* __restrict__ br2, const float* __restrict__ bo1,
    u16* __restrict__ zb, u16* __restrict__ rxb, u16* __restrict__ oi1b, int n) {
  const int lane = threadIdx.x & 63;
  const int wid = threadIdx.x >> 6;
  const int row0 = blockIdx.x * 64 + wid * 16;
  f32x4 aZ[8], aR[8], aO[8];
#pragma unroll
  for (int t = 0; t < 8; ++t) {
    aZ[t] = f32x4{0.f, 0.f, 0.f, 0.f};
    aR[t] = f32x4{0.f, 0.f, 0.f, 0.f};
    aO[t] = f32x4{0.f, 0.f, 0.f, 0.f};
  }
  const int ar = lane & 15, ak = (lane >> 4) * 8;
#pragma unroll
  for (int ks = 0; ks < 4; ++ks) {
    int r = row0 + ar;
    r = r < n ? r : n - 1;
    short8 ao = *reinterpret_cast<const short8*>(Ao + (size_t)r * DD + ks * 32 + ak);
    short8 ax = *reinterpret_cast<const short8*>(Ax + (size_t)r * DD + ks * 32 + ak);
#pragma unroll
    for (int nt = 0; nt < 8; ++nt) {
      size_t bo = (size_t)(((ks * 8 + nt) * 64 + lane) * 8);
      short8 b1 = *reinterpret_cast<const short8*>(Wu1p + bo);
      short8 b2 = *reinterpret_cast<const short8*>(Wu2p + bo);
      short8 b3 = *reinterpret_cast<const short8*>(Wr1p + bo);
      short8 b4 = *reinterpret_cast<const short8*>(Wr2p + bo);
      short8 b5 = *reinterpret_cast<const short8*>(Wo1p + bo);
      aZ[nt] = __builtin_amdgcn_mfma_f32_16x16x32_bf16(ao, b1, aZ[nt], 0, 0, 0);
      aZ[nt] = __builtin_amdgcn_mfma_f32_16x16x32_bf16(ax, b2, aZ[nt], 0, 0, 0);
      aR[nt] = __builtin_amdgcn_mfma_f32_16x16x32_bf16(ao, b3, aR[nt], 0, 0, 0);
      aR[nt] = __builtin_amdgcn_mfma_f32_16x16x32_bf16(ax, b4, aR[nt], 0, 0, 0);
      aO[nt] = __builtin_amdgcn_mfma_f32_16x16x32_bf16(ao, b5, aO[nt], 0, 0, 0);
    }
  }
  const int crow = 4 * (lane >> 4), ccol = lane & 15;
#pragma unroll
  for (int nt = 0; nt < 8; ++nt) {
    int col = ccol + nt * 16;
    float bz = bu1[col] + bu2[col];
    float br_ = br1[col] + br2[col];
    float bo_ = bo1[col];
#pragma unroll
    for (int e = 0; e < 4; ++e) {
      int r = row0 + crow + e;
      if (r < n) {
        size_t idx = (size_t)r * DD + col;
        float z = sigmoidf_(aZ[nt][e] + bz);
        float rr = sigmoidf_(aR[nt][e] + br_);
        float xv = bf2f(Ax[idx]);
        zb[idx] = f2bf(z);
        rxb[idx] = f2bf(rr * xv);
        oi1b[idx] = f2bf(aO[nt][e] + bo_);
      }
    }
  }
}

// final: oi = rx@Wo2 + bo2 + oi1 ; h = tanh(oi); out = (1-z)*x + z*h
__global__ __launch_bounds__(256) void final_gemm(const u16* __restrict__ Arx,
                                                  const u16* __restrict__ Wo2p,
                                                  const float* __restrict__ bo2,
                                                  const u16* __restrict__ oi1b,
                                                  const u16* __restrict__ zb,
                                                  const u16* __restrict__ xb,
                                                  float* __restrict__ out, int n) {
  const int lane = threadIdx.x & 63;
  const int wid = threadIdx.x >> 6;
  const int row0 = blockIdx.x * 128 + wid * 32;
  f32x4 acc[2][8];
#pragma unroll
  for (int m = 0; m < 2; ++m)
#pragma unroll
    for (int t = 0; t < 8; ++t) acc[m][t] = f32x4{0.f, 0.f, 0.f, 0.f};
  const int ar = lane & 15, ak = (lane >> 4) * 8;
#pragma unroll
  for (int ks = 0; ks < 4; ++ks) {
    short8 a[2];
#pragma unroll
    for (int m = 0; m < 2; ++m) {
      int r = row0 + m * 16 + ar;
      r = r < n ? r : n - 1;
      a[m] = *reinterpret_cast<const short8*>(Arx + (size_t)r * DD + ks * 32 + ak);
    }
#pragma unroll
    for (int nt = 0; nt < 8; ++nt) {
      short8 b = *reinterpret_cast<const short8*>(Wo2p + (((ks * 8 + nt) * 64 + lane) * 8));
#pragma unroll
      for (int m = 0; m < 2; ++m)
        acc[m][nt] = __builtin_amdgcn_mfma_f32_16x16x32_bf16(a[m], b, acc[m][nt], 0, 0, 0);
    }
  }
  const int crow = 4 * (lane >> 4), ccol = lane & 15;
#pragma unroll
  for (int m = 0; m < 2; ++m) {
#pragma unroll
    for (int nt = 0; nt < 8; ++nt) {
      int col = ccol + nt * 16;
      float bsv = bo2[col];
#pragma unroll
      for (int e = 0; e < 4; ++e) {
        int r = row0 + m * 16 + crow + e;
        if (r < n) {
          size_t idx = (size_t)r * DD + col;
          float oi = acc[m][nt][e] + bsv + bf2f(oi1b[idx]);
          float h = tanhf_(oi);
          float z = bf2f(zb[idx]);
          float xv = bf2f(xb[idx]);
          out[idx] = (1.f - z) * xv + z * h;
        }
      }
    }
  }
}

extern "C" void kernel_launch(void* const* d_in, const int* in_sizes, int n_in,
                              void* d_out, int out_size, void* d_ws, size_t ws_size,
                              hipStream_t stream) {
  const int n = in_sizes[0] / DD;  // 50000
  const int E = in_sizes[1];       // 1.6M
  const float* x_in = (const float*)d_in[0];
  const int* rows = (const int*)d_in[1];
  const int* cols = (const int*)d_in[2];
  const float* vals = (const float*)d_in[3];
  const float* Wm[10];
  const float* Bm[10];
  for (int i = 0; i < 10; ++i) {
    Wm[i] = (const float*)d_in[4 + 2 * i];
    Bm[i] = (const float*)d_in[5 + 2 * i];
  }

  char* base = (char*)d_ws;
  size_t off = 0;
  auto alloc = [&](size_t bytes) -> char* {
    char* p = base + off;
    off += (bytes + 255) & ~(size_t)255;
    return p;
  };
  u16* wpack = (u16*)alloc((size_t)10 * 16384 * 2);
  u16* x_b = (u16*)alloc((size_t)n * DD * 2);
  u16* agg_b = (u16*)alloc((size_t)n * DD * 2);  // reused as out_b
  u16* z_b = (u16*)alloc((size_t)n * DD * 2);
  u16* oi1_b = (u16*)alloc((size_t)n * DD * 2);
  u16* rx_b = (u16*)alloc((size_t)n * DD * 2);
  int* counts = (int*)alloc((size_t)n * 4);
  int* offs = (int*)alloc((size_t)(n + 1) * 4);
  int* cursor = (int*)alloc((size_t)n * 4);
  u32* epack = (u32*)alloc((size_t)E * 4);
  (void)ws_size;
  (void)n_in;
  (void)out_size;

  hipMemsetAsync(counts, 0, (size_t)n * 4, stream);
  WPtrs wp;
  for (int i = 0; i < 10; ++i) wp.w[i] = Wm[i];
  pack_weights<<<10, 256, 0, stream>>>(wp, wpack);
  count_edges<<<(E + 255) / 256, 256, 0, stream>>>(rows, counts, E);
  scan_offsets<<<1, 1024, 0, stream>>>(counts, offs, cursor, n);
  permute_edges<<<(E + 255) / 256, 256, 0, stream>>>(rows, cols, vals, cursor, epack, E);

  int gblocks = (n + 127) / 128;
  // x = mlp2(x_in, m1_*)  (fp32 input, fused 2-layer)
  mlp_fused<0><<<gblocks, 256, 0, stream>>>(x_in, wpack + 0 * 16384, Bm[0], wpack + 1 * 16384,
                                            Bm[1], x_b, n);
  // agg = segment_sum(vals * x[cols], rows)
  spmm_agg<<<(n + 3) / 4, 256, 0, stream>>>(offs, epack, x_b, agg_b, n);
  // out = mlp2(agg, m2_*)  (bf16 input, fused 2-layer)
  mlp_fused<1><<<gblocks, 256, 0, stream>>>(agg_b, wpack + 2 * 16384, Bm[2], wpack + 3 * 16384,
                                            Bm[3], agg_b, n);
  // gates
  gates_gemm<<<(n + 63) / 64, 256, 0, stream>>>(
      agg_b, x_b, wpack + 4 * 16384, wpack + 5 * 16384, wpack + 6 * 16384, wpack + 7 * 16384,
      wpack + 8 * 16384, Bm[4], Bm[5], Bm[6], Bm[7], Bm[8], z_b, rx_b, oi1_b, n);
  // final
  final_gemm<<<gblocks, 256, 0, stream>>>(rx_b, wpack + 9 * 16384, Bm[9], oi1_b, z_b, x_b,
                                          (float*)d_out, n);
}